// Round 1
// baseline (504.917 us; speedup 1.0000x reference)
//
#include <hip/hip_runtime.h>
#include <hip/hip_bf16.h>

#define Ls 256
#define Kk 9
#define Ee 128
#define Bb 512

#define ELEM(v, ci) ((ci)==0?(v).x:((ci)==1?(v).y:((ci)==2?(v).z:(v).w)))

// Kernel A: embed gather + conv1 (3,128,64 dil1) + conv2 (3,64,128 dil1) -> x2 (B,L,128)
__global__ __launch_bounds__(256) void ka_kernel(
    const int* __restrict__ text, const float* __restrict__ embed,
    const float* __restrict__ w1, const float* __restrict__ b1,
    const float* __restrict__ w2, const float* __restrict__ b2,
    float* __restrict__ x2out)
{
    __shared__ float xs0[68*128];   // embed rows, pos l0-2 .. l0+65
    __shared__ float xs1[66*64];    // conv1 out, pos l0-1 .. l0+64
    const int b  = blockIdx.y;
    const int l0 = blockIdx.x * 64;
    const int tid = threadIdx.x;

    const float4* e4 = (const float4*)embed;
    float4* xs0v = (float4*)xs0;
    #pragma unroll 1
    for (int idx = tid; idx < 68*32; idx += 256) {
        const int r = idx >> 5, c4 = idx & 31;
        const int pos = l0 + r - 2;
        float4 v = make_float4(0.f, 0.f, 0.f, 0.f);
        if (pos >= 0 && pos < Ls) {
            const int tok = text[b*Ls + pos];
            v = e4[tok*32 + c4];
        }
        xs0v[idx] = v;
    }
    __syncthreads();

    // conv1: 66 output rows x 64 channels. o = lane (coalesced w loads), row-groups per tid>>6.
    {
        const int o  = tid & 63;
        const int g  = tid >> 6;
        const int r0 = (g < 2) ? g*17 : 34 + (g-2)*16;
        const int nr = (g < 2) ? 17 : 16;
        float acc[17];
        #pragma unroll
        for (int i = 0; i < 17; ++i) acc[i] = 0.f;
        #pragma unroll 1
        for (int c4 = 0; c4 < 32; ++c4) {
            float4 xr[19];
            #pragma unroll
            for (int i = 0; i < 19; ++i) {
                int rr = r0 + i; if (rr > 67) rr = 67;   // clamp, garbage unused
                xr[i] = xs0v[rr*32 + c4];
            }
            #pragma unroll
            for (int k = 0; k < 3; ++k) {
                #pragma unroll
                for (int ci = 0; ci < 4; ++ci) {
                    const float wv = w1[(k*128 + c4*4 + ci)*64 + o];
                    #pragma unroll
                    for (int i = 0; i < 17; ++i)
                        acc[i] = fmaf(ELEM(xr[i+k], ci), wv, acc[i]);
                }
            }
        }
        const float bb1 = b1[o];
        #pragma unroll 1
        for (int i = 0; i < nr; ++i) {
            const int r1 = r0 + i;
            const int pos = l0 + r1 - 1;
            float v = 0.f;
            if (pos >= 0 && pos < Ls) v = fmaxf(acc[i] + bb1, 0.f);  // SAME pad -> zero outside
            xs1[r1*64 + o] = v;
        }
    }
    __syncthreads();

    // conv2: 64 output rows x 128 channels
    {
        const int o  = tid & 127;
        const int g  = tid >> 7;
        const int r0 = g * 32;
        const float4* xs1v = (const float4*)xs1;
        float acc[32];
        #pragma unroll
        for (int i = 0; i < 32; ++i) acc[i] = 0.f;
        #pragma unroll 1
        for (int c4 = 0; c4 < 16; ++c4) {
            float wv[12];
            #pragma unroll
            for (int k = 0; k < 3; ++k)
                #pragma unroll
                for (int ci = 0; ci < 4; ++ci)
                    wv[k*4+ci] = w2[(k*64 + c4*4 + ci)*128 + o];
            #pragma unroll
            for (int h = 0; h < 2; ++h) {
                float4 xr[18];
                #pragma unroll
                for (int i = 0; i < 18; ++i) xr[i] = xs1v[(r0 + h*16 + i)*16 + c4];
                #pragma unroll
                for (int k = 0; k < 3; ++k)
                    #pragma unroll
                    for (int ci = 0; ci < 4; ++ci) {
                        const float w = wv[k*4+ci];
                        #pragma unroll
                        for (int i = 0; i < 16; ++i)
                            acc[h*16+i] = fmaf(ELEM(xr[i+k], ci), w, acc[h*16+i]);
                    }
            }
        }
        const float bb2 = b2[o];
        #pragma unroll 1
        for (int i = 0; i < 32; ++i) {
            const int pos = l0 + r0 + i;
            x2out[((size_t)b*Ls + pos)*128 + o] = fmaxf(acc[i] + bb2, 0.f);
        }
    }
}

// Kernel B: conv3 (3,128,128 dil2) + dense (128->9) -> logits (B,L,9)
__global__ __launch_bounds__(256) void kb_kernel(
    const float* __restrict__ x2in, const float* __restrict__ w3, const float* __restrict__ b3,
    const float* __restrict__ wd, const float* __restrict__ bd,
    float* __restrict__ logits)
{
    __shared__ float smem[68*128];   // x2 tile (pos l0-2..l0+65); later reused as xl[64][132]
    const int b  = blockIdx.y;
    const int l0 = blockIdx.x * 64;
    const int tid = threadIdx.x;

    float4* sv = (float4*)smem;
    const float4* x2v = (const float4*)x2in;
    #pragma unroll 1
    for (int idx = tid; idx < 68*32; idx += 256) {
        const int r = idx >> 5, c4 = idx & 31;
        const int pos = l0 + r - 2;
        float4 v = make_float4(0.f, 0.f, 0.f, 0.f);
        if (pos >= 0 && pos < Ls) v = x2v[((size_t)b*Ls + pos)*32 + c4];
        sv[idx] = v;
    }
    __syncthreads();

    const int o  = tid & 127;
    const int g  = tid >> 7;
    const int r0 = g * 32;
    float acc[32];
    #pragma unroll
    for (int i = 0; i < 32; ++i) acc[i] = 0.f;
    #pragma unroll 1
    for (int c4 = 0; c4 < 32; ++c4) {
        float wv[12];
        #pragma unroll
        for (int k = 0; k < 3; ++k)
            #pragma unroll
            for (int ci = 0; ci < 4; ++ci)
                wv[k*4+ci] = w3[(k*128 + c4*4 + ci)*128 + o];
        #pragma unroll
        for (int h = 0; h < 2; ++h) {
            float4 xr[20];
            #pragma unroll
            for (int i = 0; i < 20; ++i) xr[i] = sv[(r0 + h*16 + i)*32 + c4];
            #pragma unroll
            for (int k = 0; k < 3; ++k)
                #pragma unroll
                for (int ci = 0; ci < 4; ++ci) {
                    const float w = wv[k*4+ci];
                    #pragma unroll
                    for (int i = 0; i < 16; ++i)
                        acc[h*16+i] = fmaf(ELEM(xr[i + 2*k], ci), w, acc[h*16+i]);  // taps -2,0,+2
                }
        }
    }
    const float bb3 = b3[o];
    #pragma unroll
    for (int i = 0; i < 32; ++i) acc[i] = fmaxf(acc[i] + bb3, 0.f);
    __syncthreads();   // all reads of x2 tile done before overwrite
    #pragma unroll 1
    for (int i = 0; i < 32; ++i) smem[(r0+i)*132 + o] = acc[i];   // pad 132: conflict-free column reads
    __syncthreads();

    // dense 128 -> 9
    #pragma unroll 1
    for (int idx = tid; idx < 64*Kk; idx += 256) {
        const int p = idx / Kk;
        const int kk = idx - p*Kk;
        float s = bd[kk];
        #pragma unroll 4
        for (int c = 0; c < 128; ++c)
            s = fmaf(smem[p*132 + c], wd[c*Kk + kk], s);
        logits[((size_t)b*Ls + l0 + p)*Kk + kk] = s;
    }
}

// Kernel C: text_lens + CRF sequence score + forward log-norm -> log_likelihood
__global__ __launch_bounds__(64) void kc_crf(
    const int* __restrict__ text, const int* __restrict__ labels,
    const float* __restrict__ trans, const float* __restrict__ logits,
    float* __restrict__ lens_out, float* __restrict__ ll_out)
{
    const int b = blockIdx.x;
    const int lane = threadIdx.x;
    __shared__ float tr[81];
    for (int idx = lane; idx < 81; idx += 64) tr[idx] = trans[idx];

    // lens = count(text != 0)
    int cnt = 0;
    #pragma unroll
    for (int t = lane; t < Ls; t += 64) cnt += (text[b*Ls + t] != 0);
    #pragma unroll
    for (int off = 1; off < 64; off <<= 1) cnt += __shfl_xor(cnt, off);
    const int len = cnt;
    if (lane == 0) lens_out[b] = (float)len;
    __syncthreads();

    // sequence score: unary + binary
    float sc = 0.f;
    #pragma unroll 1
    for (int t = lane; t < Ls; t += 64) {
        const int lab = labels[b*Ls + t];
        if (t < len)
            sc += logits[((size_t)b*Ls + t)*Kk + lab];
        if (t < Ls-1 && t < len-1) {
            const int lab1 = labels[b*Ls + t + 1];
            sc += tr[lab*Kk + lab1];
        }
    }
    #pragma unroll
    for (int off = 1; off < 64; off <<= 1) sc += __shfl_xor(sc, off);

    // forward algorithm: lane j (j<9) owns new-state j; alpha replicated in all lanes
    const int j = (lane < Kk) ? lane : 0;
    float tc[Kk];
    #pragma unroll
    for (int i = 0; i < Kk; ++i) tc[i] = tr[i*Kk + j];
    float a[Kk];
    #pragma unroll
    for (int i = 0; i < Kk; ++i) a[i] = logits[((size_t)b*Ls)*Kk + i];

    #pragma unroll 1
    for (int t = 1; t < Ls; ++t) {
        const float lg = logits[((size_t)b*Ls + t)*Kk + j];
        float m = -1e30f;
        #pragma unroll
        for (int i = 0; i < Kk; ++i) m = fmaxf(m, a[i] + tc[i]);
        float s = 0.f;
        #pragma unroll
        for (int i = 0; i < Kk; ++i) s += __expf(a[i] + tc[i] - m);
        float nv = m + __logf(s) + lg;
        if (t >= len) nv = a[j];
        #pragma unroll
        for (int i = 0; i < Kk; ++i) a[i] = __shfl(nv, i);
    }
    float m = -1e30f;
    #pragma unroll
    for (int i = 0; i < Kk; ++i) m = fmaxf(m, a[i]);
    float s = 0.f;
    #pragma unroll
    for (int i = 0; i < Kk; ++i) s += __expf(a[i] - m);
    const float log_norm = m + __logf(s);
    if (lane == 0) ll_out[b] = sc - log_norm;
}

extern "C" void kernel_launch(void* const* d_in, const int* in_sizes, int n_in,
                              void* d_out, int out_size, void* d_ws, size_t ws_size,
                              hipStream_t stream) {
    const int*   text   = (const int*)d_in[0];
    const int*   labels = (const int*)d_in[1];
    const float* embed  = (const float*)d_in[2];
    const float* w1 = (const float*)d_in[3];
    const float* b1 = (const float*)d_in[4];
    const float* w2 = (const float*)d_in[5];
    const float* b2 = (const float*)d_in[6];
    const float* w3 = (const float*)d_in[7];
    const float* b3 = (const float*)d_in[8];
    const float* wd = (const float*)d_in[9];
    const float* bd = (const float*)d_in[10];
    const float* trans = (const float*)d_in[11];

    float* out      = (float*)d_out;
    float* logits   = out;                              // B*L*K
    float* lens_out = out + (size_t)Bb*Ls*Kk;           // B (as float)
    float* ll_out   = lens_out + Bb;                    // B
    float* x2       = (float*)d_ws;                     // B*L*128 f32 = 64 MiB

    dim3 blk(256);
    dim3 grid(Ls/64, Bb);
    hipLaunchKernelGGL(ka_kernel, grid, blk, 0, stream, text, embed, w1, b1, w2, b2, x2);
    hipLaunchKernelGGL(kb_kernel, grid, blk, 0, stream, x2, w3, b3, wd, bd, logits);
    hipLaunchKernelGGL(kc_crf, dim3(Bb), dim3(64), 0, stream,
                       text, labels, trans, logits, lens_out, ll_out);
}

// Round 2
// 207.334 us; speedup vs baseline: 2.4353x; 2.4353x over previous
//
#include <hip/hip_runtime.h>
#include <hip/hip_bf16.h>

#define Ls 256
#define Kk 9
#define Bb 512

typedef short s16x8 __attribute__((ext_vector_type(8)));
typedef float f32x4 __attribute__((ext_vector_type(4)));

__device__ __forceinline__ unsigned short f2bf(float f) {
    __hip_bfloat16 h = __float2bfloat16(f);
    return *reinterpret_cast<unsigned short*>(&h);
}

// ---- weight prep: pack w1/w2/w3 into bf16 MFMA B-fragments ----
// frag layout per conv: fragid = (tap*KC + kc)*NT + nt ; lane l holds 8 bf16:
// k = kc*32 + (l>>4)*8 + j , n = nt*16 + (l&15). 16B per lane, 1024B per frag.
// conv1: 48 frags @0, conv2: 48 @48, conv3: 96 @96.
__global__ __launch_bounds__(256) void kw_prep(
    const float* __restrict__ w1, const float* __restrict__ w2, const float* __restrict__ w3,
    uint4* __restrict__ wfrag)
{
    const int gid = blockIdx.x * 256 + threadIdx.x;
    const int frag = gid >> 6;
    const int lane = gid & 63;
    if (frag >= 192) return;
    const int kb = (lane >> 4) * 8;
    const int nl = lane & 15;
    float v[8];
    if (frag < 48) {                      // conv1: KC=4, NT=4, w1[3][128][64]
        int nt = frag & 3, kc = (frag >> 2) & 3, t = frag >> 4;
        int n = nt * 16 + nl;
        #pragma unroll
        for (int j = 0; j < 8; ++j) v[j] = w1[(t * 128 + kc * 32 + kb + j) * 64 + n];
    } else if (frag < 96) {               // conv2: KC=2, NT=8, w2[3][64][128]
        int f = frag - 48; int nt = f & 7, kc = (f >> 3) & 1, t = f >> 4;
        int n = nt * 16 + nl;
        #pragma unroll
        for (int j = 0; j < 8; ++j) v[j] = w2[(t * 64 + kc * 32 + kb + j) * 128 + n];
    } else {                              // conv3: KC=4, NT=8, w3[3][128][128]
        int f = frag - 96; int nt = f & 7, kc = (f >> 3) & 3, t = f >> 5;
        int n = nt * 16 + nl;
        #pragma unroll
        for (int j = 0; j < 8; ++j) v[j] = w3[(t * 128 + kc * 32 + kb + j) * 128 + n];
    }
    uint4 o;
    o.x = (unsigned)f2bf(v[0]) | ((unsigned)f2bf(v[1]) << 16);
    o.y = (unsigned)f2bf(v[2]) | ((unsigned)f2bf(v[3]) << 16);
    o.z = (unsigned)f2bf(v[4]) | ((unsigned)f2bf(v[5]) << 16);
    o.w = (unsigned)f2bf(v[6]) | ((unsigned)f2bf(v[7]) << 16);
    wfrag[frag * 64 + lane] = o;
}

// ---- fused embed + conv1 + conv2 + conv3(dil2) + dense ----
// Per block: 64 output positions. Row index i in [0,80) <-> pos = l0-8+i.
// LDS: E (embed bf16, 82 rows stride 256B, row=i+1, rows 0/81 zero)  | aliased by X2 (80 rows, row=i)
//      X1 (conv1 bf16, 82 rows stride 128B, row=i+1, rows 0/81 zero) | aliased by X3 (f32 64 x stride 131)
// bf16 rows XOR-swizzled: byte_addr ^= (row&7)<<4  (write & read sides identical).
#define E_OFF   0
#define X2_OFF  0
#define X1_OFF  20992
#define X3_OFF  20992
#define X3_STR  131
#define SMEM_BYTES (20992 + 64 * X3_STR * 4)   // 54528 -> 3 blocks/CU

__global__ __launch_bounds__(256) void kmain(
    const int* __restrict__ text, const float* __restrict__ embed,
    const uint4* __restrict__ wfrag,
    const float* __restrict__ b1, const float* __restrict__ b2, const float* __restrict__ b3,
    const float* __restrict__ wd, const float* __restrict__ bd,
    float* __restrict__ logits)
{
    __shared__ __align__(16) char smem[SMEM_BYTES];
    const int b = blockIdx.y, l0 = blockIdx.x * 64;
    const int tid = threadIdx.x;
    const int lane = tid & 63, wv = tid >> 6;
    const int nl = lane & 15, kg = lane >> 4;

    // zero pad rows: E rows 0,81 ; X1 rows 0,81
    for (int it = tid; it < 96; it += 256) {
        char* p;
        if (it < 32)       p = smem + it * 8;
        else if (it < 64)  p = smem + 81 * 256 + (it - 32) * 8;
        else if (it < 80)  p = smem + X1_OFF + (it - 64) * 8;
        else               p = smem + X1_OFF + 81 * 128 + (it - 80) * 8;
        *(uint2*)p = make_uint2(0u, 0u);
    }
    // stage embed rows (pos l0-8 .. l0+71) as bf16, swizzled
    for (int it = tid; it < 80 * 32; it += 256) {
        const int row = (it >> 5) + 1;      // 1..80
        const int c4  = it & 31;
        const int pos = l0 - 9 + row;
        uint2 val = make_uint2(0u, 0u);
        if (pos >= 0 && pos < Ls) {
            const int tok = text[b * Ls + pos];
            const float4 e = ((const float4*)embed)[tok * 32 + c4];
            val.x = (unsigned)f2bf(e.x) | ((unsigned)f2bf(e.y) << 16);
            val.y = (unsigned)f2bf(e.z) | ((unsigned)f2bf(e.w) << 16);
        }
        int addr = row * 256 + c4 * 8;
        addr ^= (row & 7) << 4;
        *(uint2*)(smem + addr) = val;
    }
    __syncthreads();

    // ---- conv1: M=80(5 tiles), N=64 (wave -> ntile wv), K=3 taps x 128
    {
        f32x4 acc[5];
        #pragma unroll
        for (int mt = 0; mt < 5; ++mt) acc[mt] = (f32x4)0.f;
        #pragma unroll
        for (int t = 0; t < 3; ++t) {
            #pragma unroll
            for (int kc = 0; kc < 4; ++kc) {
                const s16x8 bf = *(const s16x8*)(wfrag + ((t * 4 + kc) * 4 + wv) * 64 + lane);
                #pragma unroll
                for (int mt = 0; mt < 5; ++mt) {
                    const int row = mt * 16 + nl + t;          // E row (i+1) + (t-1)
                    int addr = row * 256 + kc * 64 + kg * 16;
                    addr ^= (row & 7) << 4;
                    const s16x8 a = *(const s16x8*)(smem + addr);
                    acc[mt] = __builtin_amdgcn_mfma_f32_16x16x32_bf16(a, bf, acc[mt], 0, 0, 0);
                }
            }
        }
        const float bias = b1[wv * 16 + nl];
        #pragma unroll
        for (int mt = 0; mt < 5; ++mt) {
            #pragma unroll
            for (int r = 0; r < 4; ++r) {
                const int i = mt * 16 + kg * 4 + r;
                const int pos = l0 - 8 + i;
                float v = fmaxf(acc[mt][r] + bias, 0.f);
                if (pos < 0 || pos >= Ls) v = 0.f;
                const int row = i + 1;
                int addr = X1_OFF + row * 128 + (wv * 16 + nl) * 2;
                addr ^= (row & 7) << 4;
                *(unsigned short*)(smem + addr) = f2bf(v);
            }
        }
    }
    __syncthreads();

    // ---- conv2: M=80, N=128 (wave -> ntiles wv, wv+4), K=3 x 64
    {
        f32x4 acc[5][2];
        #pragma unroll
        for (int mt = 0; mt < 5; ++mt) { acc[mt][0] = (f32x4)0.f; acc[mt][1] = (f32x4)0.f; }
        #pragma unroll
        for (int t = 0; t < 3; ++t) {
            #pragma unroll
            for (int kc = 0; kc < 2; ++kc) {
                const s16x8 bf0 = *(const s16x8*)(wfrag + (48 + (t * 2 + kc) * 8 + wv) * 64 + lane);
                const s16x8 bf1 = *(const s16x8*)(wfrag + (48 + (t * 2 + kc) * 8 + wv + 4) * 64 + lane);
                #pragma unroll
                for (int mt = 0; mt < 5; ++mt) {
                    const int row = mt * 16 + nl + t;          // X1 row (i+1) + (t-1)
                    int addr = X1_OFF + row * 128 + kc * 64 + kg * 16;
                    addr ^= (row & 7) << 4;
                    const s16x8 a = *(const s16x8*)(smem + addr);
                    acc[mt][0] = __builtin_amdgcn_mfma_f32_16x16x32_bf16(a, bf0, acc[mt][0], 0, 0, 0);
                    acc[mt][1] = __builtin_amdgcn_mfma_f32_16x16x32_bf16(a, bf1, acc[mt][1], 0, 0, 0);
                }
            }
        }
        const float bs0 = b2[wv * 16 + nl], bs1 = b2[(wv + 4) * 16 + nl];
        #pragma unroll
        for (int mt = 0; mt < 5; ++mt) {
            #pragma unroll
            for (int r = 0; r < 4; ++r) {
                const int i = mt * 16 + kg * 4 + r;
                const int pos = l0 - 8 + i;
                float v0 = fmaxf(acc[mt][0][r] + bs0, 0.f);
                float v1 = fmaxf(acc[mt][1][r] + bs1, 0.f);
                if (pos < 0 || pos >= Ls) { v0 = 0.f; v1 = 0.f; }
                const int row = i;                              // X2 row = i
                int a0 = X2_OFF + row * 256 + (wv * 16 + nl) * 2;       a0 ^= (row & 7) << 4;
                int a1 = X2_OFF + row * 256 + ((wv + 4) * 16 + nl) * 2; a1 ^= (row & 7) << 4;
                *(unsigned short*)(smem + a0) = f2bf(v0);
                *(unsigned short*)(smem + a1) = f2bf(v1);
            }
        }
    }
    __syncthreads();

    // ---- conv3 (dil 2): M=64 (i=8..71), N=128 (wv, wv+4), K=3 x 128
    {
        f32x4 acc[4][2];
        #pragma unroll
        for (int mt = 0; mt < 4; ++mt) { acc[mt][0] = (f32x4)0.f; acc[mt][1] = (f32x4)0.f; }
        #pragma unroll
        for (int t = 0; t < 3; ++t) {
            #pragma unroll
            for (int kc = 0; kc < 4; ++kc) {
                const s16x8 bf0 = *(const s16x8*)(wfrag + (96 + (t * 4 + kc) * 8 + wv) * 64 + lane);
                const s16x8 bf1 = *(const s16x8*)(wfrag + (96 + (t * 4 + kc) * 8 + wv + 4) * 64 + lane);
                #pragma unroll
                for (int mt = 0; mt < 4; ++mt) {
                    const int row = 6 + mt * 16 + nl + 2 * t;   // X2 row = 8+mt*16+nl + 2*(t-1)
                    int addr = X2_OFF + row * 256 + kc * 64 + kg * 16;
                    addr ^= (row & 7) << 4;
                    const s16x8 a = *(const s16x8*)(smem + addr);
                    acc[mt][0] = __builtin_amdgcn_mfma_f32_16x16x32_bf16(a, bf0, acc[mt][0], 0, 0, 0);
                    acc[mt][1] = __builtin_amdgcn_mfma_f32_16x16x32_bf16(a, bf1, acc[mt][1], 0, 0, 0);
                }
            }
        }
        const float bs0 = b3[wv * 16 + nl], bs1 = b3[(wv + 4) * 16 + nl];
        float* X3 = (float*)(smem + X3_OFF);
        #pragma unroll
        for (int mt = 0; mt < 4; ++mt) {
            #pragma unroll
            for (int r = 0; r < 4; ++r) {
                const int p = mt * 16 + kg * 4 + r;             // output pos idx 0..63
                X3[p * X3_STR + wv * 16 + nl]       = fmaxf(acc[mt][0][r] + bs0, 0.f);
                X3[p * X3_STR + (wv + 4) * 16 + nl] = fmaxf(acc[mt][1][r] + bs1, 0.f);
            }
        }
    }
    __syncthreads();

    // ---- dense 128 -> 9 (f32)
    {
        const float* X3 = (const float*)(smem + X3_OFF);
        for (int it = tid; it < 64 * Kk; it += 256) {
            const int p = it / Kk;
            const int kk = it - p * Kk;
            float s = bd[kk];
            #pragma unroll 4
            for (int c = 0; c < 128; ++c)
                s = fmaf(X3[p * X3_STR + c], wd[c * Kk + kk], s);
            logits[((size_t)b * Ls + l0 + p) * Kk + kk] = s;
        }
    }
}

// ---- CRF: lens + sequence score + forward log-norm ----
__global__ __launch_bounds__(64) void kc_crf(
    const int* __restrict__ text, const int* __restrict__ labels,
    const float* __restrict__ trans, const float* __restrict__ logits,
    float* __restrict__ lens_out, float* __restrict__ ll_out)
{
    const int b = blockIdx.x;
    const int lane = threadIdx.x;
    __shared__ float tr[81];
    for (int idx = lane; idx < 81; idx += 64) tr[idx] = trans[idx];

    int cnt = 0;
    #pragma unroll
    for (int t = lane; t < Ls; t += 64) cnt += (text[b * Ls + t] != 0);
    #pragma unroll
    for (int off = 1; off < 64; off <<= 1) cnt += __shfl_xor(cnt, off);
    const int len = cnt;
    if (lane == 0) lens_out[b] = (float)len;
    __syncthreads();

    float sc = 0.f;
    #pragma unroll 1
    for (int t = lane; t < Ls; t += 64) {
        const int lab = labels[b * Ls + t];
        if (t < len)
            sc += logits[((size_t)b * Ls + t) * Kk + lab];
        if (t < Ls - 1 && t < len - 1) {
            const int lab1 = labels[b * Ls + t + 1];
            sc += tr[lab * Kk + lab1];
        }
    }
    #pragma unroll
    for (int off = 1; off < 64; off <<= 1) sc += __shfl_xor(sc, off);

    const int j = (lane < Kk) ? lane : 0;
    float tc[Kk];
    #pragma unroll
    for (int i = 0; i < Kk; ++i) tc[i] = tr[i * Kk + j];
    float a[Kk];
    #pragma unroll
    for (int i = 0; i < Kk; ++i) a[i] = logits[((size_t)b * Ls) * Kk + i];

    #pragma unroll 1
    for (int t = 1; t < Ls; ++t) {
        const float lg = logits[((size_t)b * Ls + t) * Kk + j];
        float m = -1e30f;
        #pragma unroll
        for (int i = 0; i < Kk; ++i) m = fmaxf(m, a[i] + tc[i]);
        float s = 0.f;
        #pragma unroll
        for (int i = 0; i < Kk; ++i) s += __expf(a[i] + tc[i] - m);
        float nv = m + __logf(s) + lg;
        if (t >= len) nv = a[j];
        #pragma unroll
        for (int i = 0; i < Kk; ++i) a[i] = __shfl(nv, i);
    }
    float m = -1e30f;
    #pragma unroll
    for (int i = 0; i < Kk; ++i) m = fmaxf(m, a[i]);
    float s = 0.f;
    #pragma unroll
    for (int i = 0; i < Kk; ++i) s += __expf(a[i] - m);
    const float log_norm = m + __logf(s);
    if (lane == 0) ll_out[b] = sc - log_norm;
}

extern "C" void kernel_launch(void* const* d_in, const int* in_sizes, int n_in,
                              void* d_out, int out_size, void* d_ws, size_t ws_size,
                              hipStream_t stream) {
    const int*   text   = (const int*)d_in[0];
    const int*   labels = (const int*)d_in[1];
    const float* embed  = (const float*)d_in[2];
    const float* w1 = (const float*)d_in[3];
    const float* b1 = (const float*)d_in[4];
    const float* w2 = (const float*)d_in[5];
    const float* b2 = (const float*)d_in[6];
    const float* w3 = (const float*)d_in[7];
    const float* b3 = (const float*)d_in[8];
    const float* wd = (const float*)d_in[9];
    const float* bd = (const float*)d_in[10];
    const float* trans = (const float*)d_in[11];

    float* out      = (float*)d_out;
    float* logits   = out;
    float* lens_out = out + (size_t)Bb * Ls * Kk;
    float* ll_out   = lens_out + Bb;
    uint4* wfrag    = (uint4*)d_ws;     // 192 frags x 1KB = 192KB

    hipLaunchKernelGGL(kw_prep, dim3(48), dim3(256), 0, stream, w1, w2, w3, wfrag);
    hipLaunchKernelGGL(kmain, dim3(Ls / 64, Bb), dim3(256), 0, stream,
                       text, embed, wfrag, b1, b2, b3, wd, bd, logits);
    hipLaunchKernelGGL(kc_crf, dim3(Bb), dim3(64), 0, stream,
                       text, labels, trans, logits, lens_out, ll_out);
}